// Round 8
// baseline (2036.234 us; speedup 1.0000x reference)
//
#include <hip/hip_runtime.h>
#include <stdint.h>

// ---------------------------------------------------------------------------
// SpikeMLP (all fp32 I/O):
//   h = x @ w1^T            (16384,512)x(2048,512)^T -> (16384,2048)
//   spikes,rate = LIF(h)    scan over t (4 steps, rows grouped (b,t,s))
//   out = spikes @ w2^T     (16384,2048)x(512,2048)^T -> (16384,512)
//
// Numerics contract (established round 3, DO NOT BREAK):
//   - GEMM1 (k1): per-element f32 sequential FMA over k=0..511 ascending,
//     one accumulator -> bit-exact match of the np reference's h.
//   - LIF: vv = __fmul_rn(0.95f, v); vv = __fadd_rn(vv, h); spike = vv > 1.
//   - GEMM2 is continuous in spikes {0,1} -> MFMA allowed (w2 hi+lo bf16).
//
// Round 8: x and w1 are pre-transposed (xT (512,16384), w1T (512,2048)) so
// k1 stages its [k][row] LDS tiles via global_load_lds DMA (no VGPR round
// trip, no staging VALU, no ds_write). A-fragment reads are de-aliased by
// rotating the read order by t (load-order permutation only — numerics
// identical). Round-7 k1 kept as fallback if ws is too small for xT/w1T.
//
// Workspace layout:
//   [0,256)        u32 spike counter
//   +67108864      spikes bf16 (16384 x 2048)
//   +2097152       w2_hi bf16   [if ws fits]
//   +2097152       w2_lo bf16   [if ws fits]
//   +33554432      xT fp32 (512,16384)   [if ws fits]
//   +4194304       w1T fp32 (512,2048)   [if ws fits]
// ---------------------------------------------------------------------------

typedef __attribute__((ext_vector_type(8))) short short8;   // 8 bf16 = 16 B
typedef __attribute__((ext_vector_type(4))) float f32x4;

#define AS1 __attribute__((address_space(1)))
#define AS3 __attribute__((address_space(3)))

__device__ __forceinline__ void load_lds16(const void* g, void* l) {
  __builtin_amdgcn_global_load_lds((const AS1 void*)g, (AS3 void*)l, 16, 0, 0);
}

__device__ __forceinline__ unsigned short f2bf(float f) {
  union { float f; unsigned u; } un; un.f = f;
  unsigned r = un.u + 0x7FFF + ((un.u >> 16) & 1);   // RNE
  return (unsigned short)(r >> 16);
}
__device__ __forceinline__ float bf2f(unsigned short u) {
  union { unsigned u; float f; } un; un.u = ((unsigned)u) << 16; return un.f;
}

// ---------------------------------------------------------------------------
// KT: tile transpose src (M,N) -> dst (N,M), M,N multiples of 64.
// ---------------------------------------------------------------------------
__global__ __launch_bounds__(256) void ktrans(
    const float* __restrict__ s, float* __restrict__ d, int M, int N)
{
  __shared__ float t[64][68];   // [src col][src row], 68f=272B keeps 16B align
  const int tx = threadIdx.x & 15, ty = threadIdx.x >> 4;
  const size_t r0 = (size_t)blockIdx.x * 64;
  const int    c0 = blockIdx.y * 64;
#pragma unroll
  for (int p = 0; p < 4; ++p) {
    int r = ty + 16 * p;
    float4 v = *(const float4*)&s[(r0 + r) * N + c0 + tx * 4];
    t[tx * 4 + 0][r] = v.x; t[tx * 4 + 1][r] = v.y;
    t[tx * 4 + 2][r] = v.z; t[tx * 4 + 3][r] = v.w;
  }
  __syncthreads();
#pragma unroll
  for (int p = 0; p < 4; ++p) {
    int c = ty + 16 * p;
    float4 v = *(const float4*)&t[c][tx * 4];
    *(float4*)&d[(size_t)(c0 + c) * M + r0 + tx * 4] = v;
  }
}

// ---------------------------------------------------------------------------
// K0: split w2 (fp32) into bf16 hi + lo.
// ---------------------------------------------------------------------------
__global__ __launch_bounds__(256) void k0_split(
    const float* __restrict__ w2, unsigned short* __restrict__ hi,
    unsigned short* __restrict__ lo)
{
  int i = (blockIdx.x * 256 + threadIdx.x) * 4;
  float4 w = *(const float4*)&w2[i];
  unsigned short h4[4], l4[4];
  float ws[4] = {w.x, w.y, w.z, w.w};
#pragma unroll
  for (int c = 0; c < 4; ++c) {
    unsigned short h = f2bf(ws[c]);
    h4[c] = h;
    l4[c] = f2bf(ws[c] - bf2f(h));
  }
  *(ushort4*)&hi[i] = *(const ushort4*)h4;
  *(ushort4*)&lo[i] = *(const ushort4*)l4;
}

// ---------------------------------------------------------------------------
// K1 (round 8): fused GEMM1 (f32 seq-FMA, bit-exact) + LIF via shfl.
// Inputs pre-transposed; staging = global_load_lds DMA only.
// Block tile 256 rows (4t x 64s) x 128 cols, 16x8 micro. Grid (64,16).
// LDS: sA [k][r] 32KB (r = t*64+s_local), sB [k][c] 16KB, no padding.
// ---------------------------------------------------------------------------
#define K1KT 32

__global__ __launch_bounds__(256, 2) void k1_gemm_lif(
    const float* __restrict__ xT,         // (512, 16384), col=((b*4+t)*256+s)
    const float* __restrict__ w1T,        // (512, 2048)
    unsigned short* __restrict__ spikes,  // (16384, 2048) bf16 {0,1}
    unsigned* __restrict__ cnt_out)
{
  __shared__ float sA[K1KT * 256];   // 32 KB
  __shared__ float sB[K1KT * 128];   // 16 KB

  const int tid  = threadIdx.x;
  const int lane = tid & 63;
  const int w    = tid >> 6;     // wave id == ssg
  const int tx   = tid & 15;
  const int ty   = tid >> 4;
  const int t    = ty & 3;       // this thread's time step
  const int ssg  = ty >> 2;      // s-subgroup

  const int bx = blockIdx.x;
  const int b  = bx >> 2;
  const int s0 = (bx & 3) * 64;
  const int h0 = blockIdx.y * 128;

  // DMA source decode (per lane):
  const int aT = lane >> 4;           // t-segment this lane stages for A
  const int aS = (lane & 15) * 4;     // s_local float span
  const int bK = lane >> 5;           // B: +1 k-row for upper half-wave
  const int bC = (lane & 31) * 4;     // B: col float span

  const float* aSrc = xT + ((size_t)(b * 4 + aT) << 8) + s0 + aS;  // +k*16384
  const float* bSrc = w1T + h0 + bC;                               // +k*2048

  float acc[16][8];
#pragma unroll
  for (int i = 0; i < 16; ++i)
#pragma unroll
    for (int j = 0; j < 8; ++j) acc[i][j] = 0.0f;

  const int aBase = t * 64 + ssg * 16;

  for (int k0 = 0; k0 < 512; k0 += K1KT) {
    __syncthreads();  // protect LDS from previous chunk's readers

    // A: 32 k-rows, one DMA instr each (256 floats), 8 per wave
#pragma unroll
    for (int j = 0; j < 8; ++j) {
      int kr = w * 8 + j;
      load_lds16(aSrc + (size_t)(k0 + kr) * 16384, &sA[kr * 256 + lane * 4]);
    }
    // B: 32 k-rows, 2 per DMA instr (128 floats each), 4 per wave
#pragma unroll
    for (int j = 0; j < 4; ++j) {
      int kr = (w * 4 + j) * 2;
      load_lds16(bSrc + (size_t)(k0 + kr + bK) * 2048,
                 &sB[kr * 128 + lane * 4]);
    }
    __syncthreads();  // drains vmcnt(0): DMA complete before reads

#pragma unroll
    for (int k = 0; k < K1KT; ++k) {
      const float* aRow = &sA[k * 256];
      const float* bRow = &sB[k * 128];
      // A reads rotated by t so the 4 t-subtiles hit disjoint banks
      float4 afr[4];
#pragma unroll
      for (int ig = 0; ig < 4; ++ig) {
        int igr = (ig + t) & 3;
        afr[igr] = *(const float4*)&aRow[aBase + 4 * igr];
      }
      float4 b0 = *(const float4*)&bRow[tx * 4];        // 2-way, free
      float4 b1 = *(const float4*)&bRow[64 + tx * 4];   // 2-way, free
      float av[16] = {afr[0].x, afr[0].y, afr[0].z, afr[0].w,
                      afr[1].x, afr[1].y, afr[1].z, afr[1].w,
                      afr[2].x, afr[2].y, afr[2].z, afr[2].w,
                      afr[3].x, afr[3].y, afr[3].z, afr[3].w};
      float bv[8]  = {b0.x, b0.y, b0.z, b0.w, b1.x, b1.y, b1.z, b1.w};
#pragma unroll
      for (int i = 0; i < 16; ++i)
#pragma unroll
        for (int j = 0; j < 8; ++j)
          acc[i][j] = __builtin_fmaf(av[i], bv[j], acc[i][j]);
    }
  }

  // Epilogue: LIF per (s,col) via shfl across the 4 t-owner lanes (t*16+tx).
  unsigned cnt = 0;
#pragma unroll
  for (int i = 0; i < 16; ++i) {
    unsigned short sp[8];
#pragma unroll
    for (int j = 0; j < 8; ++j) {
      float a = acc[i][j];
      float h[4];
#pragma unroll
      for (int tt = 0; tt < 4; ++tt)
        h[tt] = __shfl(a, tt * 16 + tx, 64);
      float vv = 0.0f;
      bool smine = false;
#pragma unroll
      for (int tt = 0; tt < 4; ++tt) {
        vv = __fadd_rn(__fmul_rn(0.95f, vv), h[tt]);   // numpy op-for-op
        bool s = vv > 1.0f;
        smine = (tt == t) ? s : smine;
        vv = s ? 0.0f : vv;
      }
      cnt += smine ? 1u : 0u;
      sp[j] = smine ? (unsigned short)0x3F80 : (unsigned short)0;
    }
    size_t grow = ((size_t)(b * 4 + t) << 8) + s0 + ssg * 16 + i;
    unsigned short* rowp = spikes + grow * 2048 + h0;
    *(ushort4*)&rowp[tx * 4]      = *(const ushort4*)&sp[0];
    *(ushort4*)&rowp[64 + tx * 4] = *(const ushort4*)&sp[4];
  }

#pragma unroll
  for (int off = 32; off; off >>= 1) cnt += __shfl_down(cnt, off);
  if ((tid & 63) == 0) atomicAdd(cnt_out, cnt);
}

// ---------------------------------------------------------------------------
// K1 fallback (round-7 verified, reads x/w1 directly) if ws lacks xT/w1T.
// ---------------------------------------------------------------------------
#define SA_STR 256
#define SB_STR 128

__global__ __launch_bounds__(256, 2) void k1_fb(
    const float* __restrict__ x, const float* __restrict__ w1,
    unsigned short* __restrict__ spikes, unsigned* __restrict__ cnt_out)
{
  __shared__ float sA[K1KT * SA_STR];
  __shared__ float sB[K1KT * SB_STR];

  const int tid = threadIdx.x;
  const int tx  = tid & 15;
  const int ty  = tid >> 4;
  const int t   = ty & 3;
  const int ssg = ty >> 2;

  const int bx = blockIdx.x;
  const int b  = bx >> 2;
  const int s0 = (bx & 3) * 64;
  const int h0 = blockIdx.y * 128;

  const int u  = tid >> 3;
  const int kg = tid & 7;

  float acc[16][8];
#pragma unroll
  for (int i = 0; i < 16; ++i)
#pragma unroll
    for (int j = 0; j < 8; ++j) acc[i][j] = 0.0f;

  const int aBase  = t * 64 + ssg * 16;
  const int tXor   = 4 * t;
  const int bBase0 = tx * 4;
  const int bBase1 = 64 + tx * 4;

  for (int k0 = 0; k0 < 512; k0 += K1KT) {
    __syncthreads();
#pragma unroll
    for (int j = 0; j < 8; ++j) {
      int r  = u + 32 * j;
      int tr = r >> 6, ss = r & 63;
      size_t grow = ((size_t)(b * 4 + tr) << 8) + s0 + ss;
      float4 a = *(const float4*)&x[grow * 512 + k0 + kg * 4];
      int sl = r ^ (4 * (kg ^ tr));
      sA[(4 * kg + 0) * SA_STR + sl] = a.x;
      sA[(4 * kg + 1) * SA_STR + sl] = a.y;
      sA[(4 * kg + 2) * SA_STR + sl] = a.z;
      sA[(4 * kg + 3) * SA_STR + sl] = a.w;
    }
#pragma unroll
    for (int j = 0; j < 4; ++j) {
      int c = u + 32 * j;
      float4 wv = *(const float4*)&w1[(size_t)(h0 + c) * 512 + k0 + kg * 4];
      int sl = c ^ (4 * kg);
      sB[(4 * kg + 0) * SB_STR + sl] = wv.x;
      sB[(4 * kg + 1) * SB_STR + sl] = wv.y;
      sB[(4 * kg + 2) * SB_STR + sl] = wv.z;
      sB[(4 * kg + 3) * SB_STR + sl] = wv.w;
    }
    __syncthreads();

    for (int kk = 0; kk < K1KT; kk += 4) {
      const int aXor = kk ^ tXor;
      const int bXor = kk;
#pragma unroll
      for (int k2i = 0; k2i < 4; ++k2i) {
        const int k = kk + k2i;
        const float* aRow = &sA[k * SA_STR];
        const float* bRow = &sB[k * SB_STR];
        float4 a0 = *(const float4*)&aRow[(aBase + 0)  ^ aXor];
        float4 a1 = *(const float4*)&aRow[(aBase + 4)  ^ aXor];
        float4 a2 = *(const float4*)&aRow[(aBase + 8)  ^ aXor];
        float4 a3 = *(const float4*)&aRow[(aBase + 12) ^ aXor];
        float4 b0 = *(const float4*)&bRow[bBase0 ^ bXor];
        float4 b1 = *(const float4*)&bRow[bBase1 ^ bXor];
        float av[16] = {a0.x, a0.y, a0.z, a0.w, a1.x, a1.y, a1.z, a1.w,
                        a2.x, a2.y, a2.z, a2.w, a3.x, a3.y, a3.z, a3.w};
        float bv[8]  = {b0.x, b0.y, b0.z, b0.w, b1.x, b1.y, b1.z, b1.w};
#pragma unroll
        for (int i = 0; i < 16; ++i)
#pragma unroll
          for (int j = 0; j < 8; ++j)
            acc[i][j] = __builtin_fmaf(av[i], bv[j], acc[i][j]);
      }
    }
  }

  unsigned cnt = 0;
#pragma unroll
  for (int i = 0; i < 16; ++i) {
    unsigned short sp[8];
#pragma unroll
    for (int j = 0; j < 8; ++j) {
      float a = acc[i][j];
      float h[4];
#pragma unroll
      for (int tt = 0; tt < 4; ++tt)
        h[tt] = __shfl(a, tt * 16 + tx, 64);
      float vv = 0.0f;
      bool smine = false;
#pragma unroll
      for (int tt = 0; tt < 4; ++tt) {
        vv = __fadd_rn(__fmul_rn(0.95f, vv), h[tt]);
        bool s = vv > 1.0f;
        smine = (tt == t) ? s : smine;
        vv = s ? 0.0f : vv;
      }
      cnt += smine ? 1u : 0u;
      sp[j] = smine ? (unsigned short)0x3F80 : (unsigned short)0;
    }
    size_t grow = ((size_t)(b * 4 + t) << 8) + s0 + ssg * 16 + i;
    unsigned short* rowp = spikes + grow * 2048 + h0;
    *(ushort4*)&rowp[tx * 4]      = *(const ushort4*)&sp[0];
    *(ushort4*)&rowp[64 + tx * 4] = *(const ushort4*)&sp[4];
  }

#pragma unroll
  for (int off = 32; off; off >>= 1) cnt += __shfl_down(cnt, off);
  if ((tid & 63) == 0) atomicAdd(cnt_out, cnt);
}

// ---------------------------------------------------------------------------
// K2: out = spikes @ (w2_hi + w2_lo)^T via bf16 MFMA, fp32 accum.
// ---------------------------------------------------------------------------
__global__ __launch_bounds__(256, 2) void k2_gemm_mfma(
    const unsigned short* __restrict__ spikes,
    const unsigned short* __restrict__ w2h,
    const unsigned short* __restrict__ w2l,
    float* __restrict__ out)
{
  __shared__ alignas(16) short smA [128 * 64];
  __shared__ alignas(16) short smBh[128 * 64];
  __shared__ alignas(16) short smBl[128 * 64];

  const int tid  = threadIdx.x;
  const int lane = tid & 63;
  const int quad = lane >> 4;
  const int l15  = lane & 15;
  const int wv   = tid >> 6;
  const int wm   = wv & 1;
  const int wn   = wv >> 1;

  const size_t r0 = (size_t)blockIdx.x * 128;
  const int    d0 = blockIdx.y * 128;

  int srow[4], sg8[4];
#pragma unroll
  for (int j = 0; j < 4; ++j) {
    int gi  = j * 256 + tid;
    srow[j] = gi >> 3;
    sg8[j]  = ((gi & 7) ^ (srow[j] & 7)) * 8;
  }

  const unsigned short* ab  = spikes + r0 * 2048;
  const unsigned short* bhb = w2h + (size_t)d0 * 2048;
  const unsigned short* blb = w2l + (size_t)d0 * 2048;

  f32x4 acc[4][4] = {};

  for (int k0 = 0; k0 < 2048; k0 += 64) {
    __syncthreads();
#pragma unroll
    for (int j = 0; j < 4; ++j) {
      load_lds16(ab  + (size_t)srow[j] * 2048 + k0 + sg8[j],
                 &smA [(j * 256 + tid) * 8]);
      load_lds16(bhb + (size_t)srow[j] * 2048 + k0 + sg8[j],
                 &smBh[(j * 256 + tid) * 8]);
      load_lds16(blb + (size_t)srow[j] * 2048 + k0 + sg8[j],
                 &smBl[(j * 256 + tid) * 8]);
    }
    __syncthreads();

#pragma unroll
    for (int ks = 0; ks < 2; ++ks) {
      short8 af[4], bh[4], bl[4];
#pragma unroll
      for (int mi = 0; mi < 4; ++mi) {
        int m = wm * 64 + mi * 16 + l15;
        af[mi] = ((const short8*)smA)[m * 8 + ((ks * 4 + quad) ^ (m & 7))];
      }
#pragma unroll
      for (int ni = 0; ni < 4; ++ni) {
        int n = wn * 64 + ni * 16 + l15;
        int sl = n * 8 + ((ks * 4 + quad) ^ (n & 7));
        bh[ni] = ((const short8*)smBh)[sl];
        bl[ni] = ((const short8*)smBl)[sl];
      }
#pragma unroll
      for (int mi = 0; mi < 4; ++mi)
#pragma unroll
        for (int ni = 0; ni < 4; ++ni) {
          acc[mi][ni] = __builtin_amdgcn_mfma_f32_16x16x32_bf16(
              af[mi], bh[ni], acc[mi][ni], 0, 0, 0);
          acc[mi][ni] = __builtin_amdgcn_mfma_f32_16x16x32_bf16(
              af[mi], bl[ni], acc[mi][ni], 0, 0, 0);
        }
    }
  }

  float* ob = out + r0 * 512 + d0;
#pragma unroll
  for (int mi = 0; mi < 4; ++mi)
#pragma unroll
    for (int ni = 0; ni < 4; ++ni)
#pragma unroll
      for (int r = 0; r < 4; ++r) {
        int rr = wm * 64 + mi * 16 + quad * 4 + r;
        int cc = wn * 64 + ni * 16 + l15;
        ob[(size_t)rr * 512 + cc] = acc[mi][ni][r];
      }
}

// ---------------------------------------------------------------------------
// K2 fallback (no extra ws): fp32 VALU.
// ---------------------------------------------------------------------------
#define KT 16
#define PADF 68

__global__ __launch_bounds__(256) void k2_gemm_valu(
    const unsigned short* __restrict__ spikes,
    const float* __restrict__ w2,
    float* __restrict__ out)
{
  __shared__ float sA[KT][PADF];
  __shared__ float sB[KT][PADF];

  const int tid = threadIdx.x;
  const int tx  = tid & 15;
  const int ty  = tid >> 4;
  const int lr  = tid >> 2;
  const int lg  = tid & 3;

  const size_t r0 = (size_t)blockIdx.x * 64;
  const int    d0 = blockIdx.y * 64;

  float acc[4][4];
#pragma unroll
  for (int i = 0; i < 4; ++i)
#pragma unroll
    for (int j = 0; j < 4; ++j) acc[i][j] = 0.0f;

  for (int k0 = 0; k0 < 2048; k0 += KT) {
    __syncthreads();
    ushort4 av = *(const ushort4*)&spikes[(r0 + lr) * 2048 + k0 + lg * 4];
    float4  bv = *(const float4*)&w2[(size_t)(d0 + lr) * 2048 + k0 + lg * 4];
    sA[lg * 4 + 0][lr] = bf2f(av.x); sA[lg * 4 + 1][lr] = bf2f(av.y);
    sA[lg * 4 + 2][lr] = bf2f(av.z); sA[lg * 4 + 3][lr] = bf2f(av.w);
    sB[lg * 4 + 0][lr] = bv.x; sB[lg * 4 + 1][lr] = bv.y;
    sB[lg * 4 + 2][lr] = bv.z; sB[lg * 4 + 3][lr] = bv.w;
    __syncthreads();

#pragma unroll
    for (int k = 0; k < KT; ++k) {
      float4 a4 = *(const float4*)&sA[k][ty * 4];
      float4 b4 = *(const float4*)&sB[k][tx * 4];
      float aa[4] = {a4.x, a4.y, a4.z, a4.w};
      float bb[4] = {b4.x, b4.y, b4.z, b4.w};
#pragma unroll
      for (int i = 0; i < 4; ++i)
#pragma unroll
        for (int j = 0; j < 4; ++j)
          acc[i][j] = __builtin_fmaf(aa[i], bb[j], acc[i][j]);
    }
  }

#pragma unroll
  for (int i = 0; i < 4; ++i) {
    float4 o = make_float4(acc[i][0], acc[i][1], acc[i][2], acc[i][3]);
    *(float4*)&out[(r0 + ty * 4 + i) * 512 + d0 + tx * 4] = o;
  }
}

// ---------------------------------------------------------------------------
// K3: rate = count / 33554432 -> fp32 at d_out[8388608]
// ---------------------------------------------------------------------------
__global__ void k3_rate(const unsigned* __restrict__ cnt, float* __restrict__ dst) {
  dst[0] = (float)((double)(*cnt) / 33554432.0);
}

extern "C" void kernel_launch(void* const* d_in, const int* in_sizes, int n_in,
                              void* d_out, int out_size, void* d_ws, size_t ws_size,
                              hipStream_t stream) {
  const float* x  = (const float*)d_in[0];
  const float* w1 = (const float*)d_in[1];
  const float* w2 = (const float*)d_in[2];
  float* out = (float*)d_out;

  char* wsb = (char*)d_ws;
  unsigned* cnt = (unsigned*)wsb;
  unsigned short* spikes = (unsigned short*)(wsb + 256);
  const size_t SPIKES_B = (size_t)16384 * 2048 * 2;     // 64 MiB
  const size_t W2S_B    = (size_t)512 * 2048 * 2;       // 2 MiB each
  unsigned short* w2h = (unsigned short*)(wsb + 256 + SPIKES_B);
  unsigned short* w2l = w2h + (size_t)512 * 2048;
  float* xT  = (float*)(wsb + 256 + SPIKES_B + 2 * W2S_B);
  float* w1T = xT + (size_t)512 * 16384;

  const size_t NEED_SPLIT = 256 + SPIKES_B + 2 * W2S_B;
  const size_t NEED_ALL   = NEED_SPLIT + (size_t)512 * 16384 * 4
                                       + (size_t)512 * 2048 * 4;

  hipMemsetAsync(d_ws, 0, 256, stream);  // zero the spike counter

  if (ws_size >= NEED_ALL) {
    hipLaunchKernelGGL(ktrans, dim3(256, 8), dim3(256), 0, stream,
                       x, xT, 16384, 512);
    hipLaunchKernelGGL(ktrans, dim3(32, 8), dim3(256), 0, stream,
                       w1, w1T, 2048, 512);
    hipLaunchKernelGGL(k1_gemm_lif, dim3(64, 16), dim3(256), 0, stream,
                       xT, w1T, spikes, cnt);
  } else {
    hipLaunchKernelGGL(k1_fb, dim3(64, 16), dim3(256), 0, stream,
                       x, w1, spikes, cnt);
  }

  if (ws_size >= NEED_SPLIT) {
    hipLaunchKernelGGL(k0_split, dim3(1024), dim3(256), 0, stream, w2, w2h, w2l);
    hipLaunchKernelGGL(k2_gemm_mfma, dim3(128, 4), dim3(256), 0, stream,
                       spikes, w2h, w2l, out);
  } else {
    hipLaunchKernelGGL(k2_gemm_valu, dim3(256, 8), dim3(256), 0, stream,
                       spikes, w2, out);
  }

  hipLaunchKernelGGL(k3_rate, dim3(1), dim3(1), 0, stream, cnt, out + 8388608);
}